// Round 6
// baseline (178.395 us; speedup 1.0000x reference)
//
#include <hip/hip_runtime.h>
#include <hip/hip_bf16.h>

// Flash attention fwd. q[B,N,D], k[B,D,N] (=K^T), v[B,N,D] fp32 in, fp32 out.
// B=16, N=2048, D=128. fp16 MFMA path, fp32 accumulate.
// R6: LDS-pipe-bound fix. BM=128 (grid 256 = 1 block/CU), 4 waves x 32 q-rows
// (2 strips of 16). Each K/V b128 fragment read feeds 2 MFMAs (both strips);
// each staged K/V tile serves 128 rows. Per-row LDS traffic halves.
// Register-prefetch pipeline + XCD swizzle (2 batches/XCD -> K/V in L2) kept.
// MFMA 16x16x32 layouts (learn_hip m89/m91/m120, dtype-indep C/D):
//   A: lane holds A[m=lane&15][k=(lane>>4)*8+j]
//   B: lane holds B[k=(lane>>4)*8+j][n=lane&15]
//   C/D: lane reg r holds C[row=(lane>>4)*4+r][col=lane&15]
// K/V in LDS transposed, 16B-granule XOR swizzle (<=2-way banks, free m136).
// P scratch swzP2(row)=((row>>1)&6)|(row&1): writes conflict-free (rows
// r,r+4,r+8,r+12 -> distinct granules), reads 2-way (free).

typedef __attribute__((ext_vector_type(8))) _Float16 f16x8;
typedef __attribute__((ext_vector_type(4))) float f32x4;

constexpr int Bz = 16;
constexpr int Nn = 2048;
constexpr int Dd = 128;
constexpr int BM = 128;  // q rows per block (4 waves x 32)
constexpr int BN = 64;   // keys per iteration

__device__ __forceinline__ int swz(int r) { return (r ^ (r >> 3)) & 7; }
__device__ __forceinline__ int swzP2(int row) { return ((row >> 1) & 6) | (row & 1); }

__device__ __forceinline__ uint packh2(float a, float b) {
    union { _Float16 h[2]; uint u; } p;
    p.h[0] = (_Float16)a; p.h[1] = (_Float16)b;
    return p.u;
}
__device__ __forceinline__ ushort f2h_bits(float a) {
    union { _Float16 h; ushort u; } p;
    p.h = (_Float16)a;
    return p.u;
}

template <int CTRL>
__device__ __forceinline__ float dpp_mov(float x) {
    int y = __builtin_amdgcn_mov_dpp(__builtin_bit_cast(int, x), CTRL, 0xF, 0xF, true);
    return __builtin_bit_cast(float, y);
}
// 16-lane all-reduce: quad_perm xor1/xor2, then row_ror:4, row_ror:8.
template <typename Op>
__device__ __forceinline__ float allred16(float x, Op op) {
    x = op(x, dpp_mov<0xB1>(x));    // quad_perm [1,0,3,2]
    x = op(x, dpp_mov<0x4E>(x));    // quad_perm [2,3,0,1]
    x = op(x, dpp_mov<0x124>(x));   // row_ror:4
    x = op(x, dpp_mov<0x128>(x));   // row_ror:8
    return x;
}

__global__ __launch_bounds__(256, 1)
void fattn_kernel(const float* __restrict__ qg,
                  const float* __restrict__ kg,
                  const float* __restrict__ vg,
                  float* __restrict__ og)
{
    __shared__ ushort lds_k[BN * Dd];      // [kk][d ^ (swz(kk)<<3)]  16 KB
    __shared__ ushort lds_v[Dd * BN];      // [d][kk ^ (swz(d)<<3)]   16 KB
    __shared__ ushort lds_p[4][32 * BN];   // per-wave P scratch (32 rows) 16 KB
    uint* const lds_k32 = (uint*)lds_k;
    uint* const lds_v32 = (uint*)lds_v;

    // XCD-aware swizzle (perf heuristic: dispatch XCD = bid % 8).
    // 256 blocks: XCD x serves batches {2x,2x+1}; K+V fp32 set = 4MB = L2.
    const int bid  = blockIdx.x;
    const int xcd  = bid & 7;
    const int idx  = bid >> 3;            // 0..31
    const int b    = xcd * 2 + (idx >> 4);
    const int q0   = (idx & 15) * BM;
    const int tid  = threadIdx.x;
    const int wv   = tid >> 6;
    const int lane = tid & 63;
    const int quad = lane >> 4;
    const int l15  = lane & 15;

    // ---- Q fragments (A operand), 2 strips of 16 rows, fp32 -> fp16 ----
    f16x8 qf[2][4];
    #pragma unroll
    for (int s = 0; s < 2; ++s) {
        const float* qp = qg + (size_t)(b * Nn + q0 + wv * 32 + s * 16 + l15) * Dd + quad * 8;
        #pragma unroll
        for (int c = 0; c < 4; ++c) {
            float4 x0 = *(const float4*)(qp + c * 32);
            float4 x1 = *(const float4*)(qp + c * 32 + 4);
            const float xv[8] = {x0.x, x0.y, x0.z, x0.w, x1.x, x1.y, x1.z, x1.w};
            union { f16x8 v; _Float16 e[8]; } u;
            #pragma unroll
            for (int j = 0; j < 8; ++j) u.e[j] = (_Float16)xv[j];
            qf[s][c] = u.v;
        }
    }

    f32x4 accO[2][8];
    float m_i[2][4], l_i[2][4];
    #pragma unroll
    for (int s = 0; s < 2; ++s) {
        #pragma unroll
        for (int i = 0; i < 8; ++i) accO[s][i] = f32x4{0.f, 0.f, 0.f, 0.f};
        #pragma unroll
        for (int r = 0; r < 4; ++r) { m_i[s][r] = -1e30f; l_i[s][r] = 0.f; }
    }

    // staging thread mapping (constant across iterations)
    const int kgrp = tid & 7;    // K: n-group (8 n's)
    const int krow = tid >> 3;   // K: d-pair 0..31
    const int vgrp = tid & 15;   // V: d-group (8 d's)
    const int vrow = tid >> 4;   // V: kk-pair 0..15

    const float* kbase = kg + (size_t)b * Dd * Nn;
    const float* vbase = vg + (size_t)b * Nn * Dd;

    // prefetch register buffers: 16 float4 in flight across compute
    float4 kr[8], vr[8];
    auto issue_loads = [&](int n0) {
        #pragma unroll
        for (int pass = 0; pass < 2; ++pass) {
            const int d0 = krow * 2 + pass * 64;
            const float* s0 = kbase + (size_t)d0 * Nn + n0 + kgrp * 8;
            kr[pass * 4 + 0] = ((const float4*)s0)[0];
            kr[pass * 4 + 1] = ((const float4*)s0)[1];
            kr[pass * 4 + 2] = ((const float4*)(s0 + Nn))[0];
            kr[pass * 4 + 3] = ((const float4*)(s0 + Nn))[1];
            const int kk0 = vrow * 2 + pass * 32;
            const float* t0 = vbase + (size_t)(n0 + kk0) * Dd + vgrp * 8;
            vr[pass * 4 + 0] = ((const float4*)t0)[0];
            vr[pass * 4 + 1] = ((const float4*)t0)[1];
            vr[pass * 4 + 2] = ((const float4*)(t0 + Dd))[0];
            vr[pass * 4 + 3] = ((const float4*)(t0 + Dd))[1];
        }
    };
    auto write_lds = [&]() {
        #pragma unroll
        for (int pass = 0; pass < 2; ++pass) {
            const int d0 = krow * 2 + pass * 64;
            const float* av = (const float*)&kr[pass * 4 + 0];  // row d0
            const float* bv = (const float*)&kr[pass * 4 + 2];  // row d0+1
            #pragma unroll
            for (int j = 0; j < 8; ++j) {
                const int n = kgrp * 8 + j;
                lds_k32[n * (Dd / 2) + ((d0 >> 1) ^ (swz(n) << 2))] = packh2(av[j], bv[j]);
            }
            const int kk0 = vrow * 2 + pass * 32;
            const float* cv = (const float*)&vr[pass * 4 + 0];  // row kk0
            const float* dv = (const float*)&vr[pass * 4 + 2];  // row kk0+1
            #pragma unroll
            for (int j = 0; j < 8; ++j) {
                const int dd = vgrp * 8 + j;
                lds_v32[dd * (BN / 2) + ((kk0 >> 1) ^ (swz(dd) << 2))] = packh2(cv[j], dv[j]);
            }
        }
    };

    issue_loads(0);

    for (int it = 0; it < Nn / BN; ++it) {
        write_lds();          // vmcnt wait on kr/vr lands here
        __syncthreads();

        // prefetch next tile (wraps on last iter: dead load, branch-free)
        issue_loads(((it + 1) & 31) * BN);

        // ---- S = Q K^T : per strip 4 tiles of 16x16; K-frag read once,
        //      used by both strips ----
        f32x4 accS[2][4];
        #pragma unroll
        for (int kt = 0; kt < 4; ++kt) {
            f32x4 s0 = f32x4{0.f, 0.f, 0.f, 0.f};
            f32x4 s1 = f32x4{0.f, 0.f, 0.f, 0.f};
            const int row = kt * 16 + l15;          // kk index (B-frag n)
            const int sw = swz(row) << 3;
            #pragma unroll
            for (int c = 0; c < 4; ++c) {
                f16x8 kf = *(const f16x8*)&lds_k[row * Dd + ((c * 32 + quad * 8) ^ sw)];
                s0 = __builtin_amdgcn_mfma_f32_16x16x32_f16(qf[0][c], kf, s0, 0, 0, 0);
                s1 = __builtin_amdgcn_mfma_f32_16x16x32_f16(qf[1][c], kf, s1, 0, 0, 0);
            }
            accS[0][kt] = s0;
            accS[1][kt] = s1;
        }

        // ---- online softmax per strip (row = quad*4 + r), DPP reductions ----
        #pragma unroll
        for (int s = 0; s < 2; ++s) {
            float alpha[4];
            #pragma unroll
            for (int r = 0; r < 4; ++r) {
                float t = fmaxf(fmaxf(accS[s][0][r], accS[s][1][r]),
                                fmaxf(accS[s][2][r], accS[s][3][r]));
                t = allred16(t, [](float a, float bb) { return fmaxf(a, bb); });
                const float mn = fmaxf(m_i[s][r], t);
                alpha[r] = __expf(m_i[s][r] - mn);
                m_i[s][r] = mn;
            }
            #pragma unroll
            for (int r = 0; r < 4; ++r) {
                float local = 0.f;
                #pragma unroll
                for (int kt = 0; kt < 4; ++kt) {
                    const float p = __expf(accS[s][kt][r] - m_i[s][r]);
                    accS[s][kt][r] = p;
                    local += p;
                }
                l_i[s][r] = l_i[s][r] * alpha[r] + local;   // per-lane partial
            }
            #pragma unroll
            for (int dt = 0; dt < 8; ++dt) {
                #pragma unroll
                for (int r = 0; r < 4; ++r)
                    accO[s][dt][r] *= alpha[r];
            }
        }

        // ---- P (C layout) -> LDS -> A-operand layout (wave-private) ----
        ushort* pl = &lds_p[wv][0];
        #pragma unroll
        for (int s = 0; s < 2; ++s) {
            #pragma unroll
            for (int kt = 0; kt < 4; ++kt) {
                #pragma unroll
                for (int r = 0; r < 4; ++r) {
                    const int lr = s * 16 + quad * 4 + r;
                    const int col = kt * 16 + l15;
                    pl[lr * BN + (col ^ (swzP2(lr) << 3))] = f2h_bits(accS[s][kt][r]);
                }
            }
        }
        f16x8 pf[2][2];
        #pragma unroll
        for (int s = 0; s < 2; ++s) {
            const int lr = s * 16 + l15;
            const int sw = swzP2(lr) << 3;
            pf[s][0] = *(const f16x8*)&pl[lr * BN + ((quad * 8) ^ sw)];
            pf[s][1] = *(const f16x8*)&pl[lr * BN + ((32 + quad * 8) ^ sw)];
        }

        // ---- O += P V : 8 dout tiles; V-frags read once, feed both strips ----
        #pragma unroll
        for (int dt = 0; dt < 8; ++dt) {
            const int row = dt * 16 + l15;          // dout index (B-frag n)
            const int sw = swz(row) << 3;
            f16x8 vf0 = *(const f16x8*)&lds_v[row * BN + ((quad * 8) ^ sw)];
            f16x8 vf1 = *(const f16x8*)&lds_v[row * BN + ((32 + quad * 8) ^ sw)];
            #pragma unroll
            for (int s = 0; s < 2; ++s) {
                accO[s][dt] = __builtin_amdgcn_mfma_f32_16x16x32_f16(pf[s][0], vf0, accO[s][dt], 0, 0, 0);
                accO[s][dt] = __builtin_amdgcn_mfma_f32_16x16x32_f16(pf[s][1], vf1, accO[s][dt], 0, 0, 0);
            }
        }
        __syncthreads();   // all waves done reading lds_k/lds_v
    }

    // ---- epilogue: reduce l (16 lanes per row), O/l, fp32 store ----
    #pragma unroll
    for (int s = 0; s < 2; ++s) {
        float inv[4];
        #pragma unroll
        for (int r = 0; r < 4; ++r) {
            const float l = allred16(l_i[s][r], [](float a, float bb) { return a + bb; });
            inv[r] = 1.f / l;
        }
        float* ob = og + (size_t)(b * Nn + q0 + wv * 32 + s * 16) * Dd;
        #pragma unroll
        for (int dt = 0; dt < 8; ++dt) {
            #pragma unroll
            for (int r = 0; r < 4; ++r) {
                const int row = quad * 4 + r;
                const int col = dt * 16 + l15;
                ob[(size_t)row * Dd + col] = accO[s][dt][r] * inv[r];
            }
        }
    }
}

extern "C" void kernel_launch(void* const* d_in, const int* in_sizes, int n_in,
                              void* d_out, int out_size, void* d_ws, size_t ws_size,
                              hipStream_t stream) {
    const float* q = (const float*)d_in[0];
    const float* k = (const float*)d_in[1];
    const float* v = (const float*)d_in[2];
    float* o = (float*)d_out;
    (void)d_ws; (void)ws_size; (void)in_sizes; (void)n_in; (void)out_size;
    fattn_kernel<<<dim3(Bz * (Nn / BM)), dim3(256), 0, stream>>>(q, k, v, o);
}

// Round 7
// 150.947 us; speedup vs baseline: 1.1818x; 1.1818x over previous
//
#include <hip/hip_runtime.h>
#include <hip/hip_bf16.h>

// Flash attention fwd. q[B,N,D], k[B,D,N] (=K^T), v[B,N,D] fp32 in, fp32 out.
// B=16, N=2048, D=128. fp16 MFMA, fp32 accumulate.
// R7: transposed-operand convention + 512-thread blocks.
//  - Block = 512 thr (8 waves x 16 q rows) = BM 128; grid 256 = 1 block/CU,
//    8 waves/CU (2/SIMD, same TLP as R5); staged K/V tile serves 128 rows.
//  - GEMM1 swapped: S^T = Kfrag x Qfrag (same LDS addresses as before) ->
//    softmax row = q = l15 (per-lane): reductions are 2 shfl_xor, alpha/m/l
//    scalar per lane.
//  - GEMM2 swapped: O^T = V^Tfrag x P^Tfrag; P^T C-layout has 4 consecutive
//    kk per lane -> P round trip = 4 ds_write_b64 + 2 ds_read_b128 (PK=72
//    pad -> structurally conflict-free). Epilogue = float4 stores.
// MFMA 16x16x32 layouts (learn_hip m89/m91/m120, dtype-indep C/D):
//   A: lane holds A[m=l15][k=quad*8+j]
//   B: lane holds B[k=quad*8+j][n=l15]
//   C/D: lane reg r holds C[row=quad*4+r][col=l15]
// K/V in LDS transposed, 16B-granule XOR swizzle (<=2-way banks, free m136).
// Register-prefetch pipeline + XCD swizzle (2 batches/XCD -> K/V in L2) kept.

typedef __attribute__((ext_vector_type(8))) _Float16 f16x8;
typedef __attribute__((ext_vector_type(4))) float f32x4;

constexpr int Bz = 16;
constexpr int Nn = 2048;
constexpr int Dd = 128;
constexpr int BM = 128;  // q rows per block (8 waves x 16)
constexpr int BN = 64;   // keys per iteration
constexpr int PK = 72;   // P scratch row stride (ushorts), pad vs 64

__device__ __forceinline__ int swz(int r) { return (r ^ (r >> 3)) & 7; }

__device__ __forceinline__ uint packh2(float a, float b) {
    union { _Float16 h[2]; uint u; } p;
    p.h[0] = (_Float16)a; p.h[1] = (_Float16)b;
    return p.u;
}

__global__ __launch_bounds__(512, 2)
void fattn_kernel(const float* __restrict__ qg,
                  const float* __restrict__ kg,
                  const float* __restrict__ vg,
                  float* __restrict__ og)
{
    __shared__ ushort lds_k[BN * Dd];      // [kk][d ^ (swz(kk)<<3)]   16 KB
    __shared__ ushort lds_v[Dd * BN];      // [d][kk ^ (swz(d)<<3)]    16 KB
    __shared__ ushort lds_p[8 * 16 * PK];  // per-wave P^T [q][kk]     18 KB
    uint* const lds_k32 = (uint*)lds_k;
    uint* const lds_v32 = (uint*)lds_v;

    // XCD-aware swizzle (perf heuristic: dispatch XCD = bid % 8).
    // 256 blocks: XCD x serves batches {2x,2x+1}; K+V fp32 set = 4MB = L2.
    const int bid  = blockIdx.x;
    const int xcd  = bid & 7;
    const int idx  = bid >> 3;            // 0..31
    const int b    = xcd * 2 + (idx >> 4);
    const int q0   = (idx & 15) * BM;
    const int tid  = threadIdx.x;
    const int wv   = tid >> 6;            // 0..7
    const int lane = tid & 63;
    const int quad = lane >> 4;
    const int l15  = lane & 15;

    // ---- Q fragments (B operand now; same data layout), fp32 -> fp16 ----
    f16x8 qf[4];
    {
        const float* qp = qg + (size_t)(b * Nn + q0 + wv * 16 + l15) * Dd + quad * 8;
        #pragma unroll
        for (int c = 0; c < 4; ++c) {
            float4 x0 = *(const float4*)(qp + c * 32);
            float4 x1 = *(const float4*)(qp + c * 32 + 4);
            const float xv[8] = {x0.x, x0.y, x0.z, x0.w, x1.x, x1.y, x1.z, x1.w};
            union { f16x8 v; _Float16 e[8]; } u;
            #pragma unroll
            for (int j = 0; j < 8; ++j) u.e[j] = (_Float16)xv[j];
            qf[c] = u.v;
        }
    }

    // O^T accumulator: accO[dt][r] = O[q=l15][dout=dt*16+quad*4+r]
    f32x4 accO[8];
    #pragma unroll
    for (int i = 0; i < 8; ++i) accO[i] = f32x4{0.f, 0.f, 0.f, 0.f};
    float m_i = -1e30f, l_i = 0.f;        // per-lane (q = l15)

    // staging thread mapping (512 threads, one pass each)
    const int kgrp = tid & 7;    // K: n-group (8 n's)
    const int krow = tid >> 3;   // K: d-pair 0..63
    const int vgrp = tid & 15;   // V: d-group (8 d's)
    const int vrow = tid >> 4;   // V: kk-pair 0..31

    const float* kbase = kg + (size_t)b * Dd * Nn;
    const float* vbase = vg + (size_t)b * Nn * Dd;

    // prefetch register buffers: 8 float4 in flight across compute
    float4 kr[4], vr[4];
    auto issue_loads = [&](int n0) {
        const int d0 = krow * 2;
        const float* s0 = kbase + (size_t)d0 * Nn + n0 + kgrp * 8;
        kr[0] = ((const float4*)s0)[0];
        kr[1] = ((const float4*)s0)[1];
        kr[2] = ((const float4*)(s0 + Nn))[0];
        kr[3] = ((const float4*)(s0 + Nn))[1];
        const int kk0 = vrow * 2;
        const float* t0 = vbase + (size_t)(n0 + kk0) * Dd + vgrp * 8;
        vr[0] = ((const float4*)t0)[0];
        vr[1] = ((const float4*)t0)[1];
        vr[2] = ((const float4*)(t0 + Dd))[0];
        vr[3] = ((const float4*)(t0 + Dd))[1];
    };
    auto write_lds = [&]() {
        const int d0 = krow * 2;
        const float* av = (const float*)&kr[0];  // K row d0
        const float* bv = (const float*)&kr[2];  // K row d0+1
        #pragma unroll
        for (int j = 0; j < 8; ++j) {
            const int n = kgrp * 8 + j;
            lds_k32[n * (Dd / 2) + ((d0 >> 1) ^ (swz(n) << 2))] = packh2(av[j], bv[j]);
        }
        const int kk0 = vrow * 2;
        const float* cv = (const float*)&vr[0];  // V row kk0
        const float* dv = (const float*)&vr[2];  // V row kk0+1
        #pragma unroll
        for (int j = 0; j < 8; ++j) {
            const int dd = vgrp * 8 + j;
            lds_v32[dd * (BN / 2) + ((kk0 >> 1) ^ (swz(dd) << 2))] = packh2(cv[j], dv[j]);
        }
    };

    issue_loads(0);

    for (int it = 0; it < Nn / BN; ++it) {
        write_lds();          // vmcnt wait on kr/vr lands here
        __syncthreads();

        // prefetch next tile (wraps on last iter: dead load, branch-free)
        issue_loads(((it + 1) & 31) * BN);

        // ---- S^T = K' x Q^T : 4 kk-tiles of 16; A=K-frag, B=Q-frag ----
        // accS[kt][r] = S[q=l15][kk = kt*16 + quad*4 + r]
        f32x4 accS[4];
        #pragma unroll
        for (int kt = 0; kt < 4; ++kt) {
            f32x4 s = f32x4{0.f, 0.f, 0.f, 0.f};
            const int row = kt * 16 + l15;          // kk index (A-frag m)
            const int sw = swz(row) << 3;
            #pragma unroll
            for (int c = 0; c < 4; ++c) {
                f16x8 kf = *(const f16x8*)&lds_k[row * Dd + ((c * 32 + quad * 8) ^ sw)];
                s = __builtin_amdgcn_mfma_f32_16x16x32_f16(kf, qf[c], s, 0, 0, 0);
            }
            accS[kt] = s;
        }

        // ---- online softmax, per-lane row (q = l15) ----
        float mx = accS[0][0];
        #pragma unroll
        for (int kt = 0; kt < 4; ++kt)
            #pragma unroll
            for (int r = 0; r < 4; ++r)
                mx = fmaxf(mx, accS[kt][r]);
        mx = fmaxf(mx, __shfl_xor(mx, 16, 64));
        mx = fmaxf(mx, __shfl_xor(mx, 32, 64));
        const float mn = fmaxf(m_i, mx);
        const float alpha = __expf(m_i - mn);
        m_i = mn;
        float local = 0.f;
        #pragma unroll
        for (int kt = 0; kt < 4; ++kt)
            #pragma unroll
            for (int r = 0; r < 4; ++r) {
                const float p = __expf(accS[kt][r] - mn);
                accS[kt][r] = p;
                local += p;
            }
        l_i = l_i * alpha + local;   // per-lane partial; cross-quad at end
        #pragma unroll
        for (int dt = 0; dt < 8; ++dt)
            #pragma unroll
            for (int r = 0; r < 4; ++r)
                accO[dt][r] *= alpha;

        // ---- P^T -> LDS [q][kk] (wave-private): 4 consecutive kk/lane ----
        ushort* pl = lds_p + wv * 16 * PK;
        #pragma unroll
        for (int kt = 0; kt < 4; ++kt) {
            uint2 w;
            w.x = packh2(accS[kt][0], accS[kt][1]);
            w.y = packh2(accS[kt][2], accS[kt][3]);
            *(uint2*)(pl + l15 * PK + kt * 16 + quad * 4) = w;   // ds_write_b64
        }
        f16x8 pf0 = *(const f16x8*)&pl[l15 * PK + quad * 8];
        f16x8 pf1 = *(const f16x8*)&pl[l15 * PK + 32 + quad * 8];

        // ---- O^T += V' x P^T : 8 dout tiles; A=V^T-frag, B=P^T-frag ----
        #pragma unroll
        for (int dt = 0; dt < 8; ++dt) {
            const int row = dt * 16 + l15;          // dout index (A-frag m)
            const int sw = swz(row) << 3;
            f16x8 vf0 = *(const f16x8*)&lds_v[row * BN + ((quad * 8) ^ sw)];
            f16x8 vf1 = *(const f16x8*)&lds_v[row * BN + ((32 + quad * 8) ^ sw)];
            accO[dt] = __builtin_amdgcn_mfma_f32_16x16x32_f16(vf0, pf0, accO[dt], 0, 0, 0);
            accO[dt] = __builtin_amdgcn_mfma_f32_16x16x32_f16(vf1, pf1, accO[dt], 0, 0, 0);
        }
        __syncthreads();   // all waves done reading lds_k/lds_v
    }

    // ---- epilogue: reduce l across quads, O/l, float4 stores ----
    float l = l_i;
    l += __shfl_xor(l, 16, 64);
    l += __shfl_xor(l, 32, 64);
    const float inv = 1.f / l;
    float* ob = og + (size_t)(b * Nn + q0 + wv * 16 + l15) * Dd;
    #pragma unroll
    for (int dt = 0; dt < 8; ++dt) {
        float4 val;
        val.x = accO[dt][0] * inv;
        val.y = accO[dt][1] * inv;
        val.z = accO[dt][2] * inv;
        val.w = accO[dt][3] * inv;
        *(float4*)(ob + dt * 16 + quad * 4) = val;
    }
}

extern "C" void kernel_launch(void* const* d_in, const int* in_sizes, int n_in,
                              void* d_out, int out_size, void* d_ws, size_t ws_size,
                              hipStream_t stream) {
    const float* q = (const float*)d_in[0];
    const float* k = (const float*)d_in[1];
    const float* v = (const float*)d_in[2];
    float* o = (float*)d_out;
    (void)d_ws; (void)ws_size; (void)in_sizes; (void)n_in; (void)out_size;
    fattn_kernel<<<dim3(Bz * (Nn / BM)), dim3(512), 0, stream>>>(q, k, v, o);
}

// Round 8
// 145.014 us; speedup vs baseline: 1.2302x; 1.0409x over previous
//
#include <hip/hip_runtime.h>
#include <hip/hip_bf16.h>

// Flash attention fwd. q[B,N,D], k[B,D,N] (=K^T), v[B,N,D] fp32 in, fp32 out.
// B=16, N=2048, D=128. fp16 MFMA (32x32x16), fp32 accumulate.
// R8: producer/consumer wave specialization + 32x32x16 MFMA.
//  - Block 512 thr: waves 0-3 = consumers (32 q-rows each, BM=128),
//    waves 4-7 = producers (double-buffered K/V staging, BN=32/iter).
//    Grid 256 = 1 block/CU, 8 waves/CU (2/SIMD). One barrier per iter.
//  - 32x32x16 MFMA: one b128 A-frag read feeds 16K MACs (2x FLOP/LDS-byte
//    vs 16x16x32). C/D layout (m74/m101): col=lane&31,
//    row=(reg&3)+8*(reg>>2)+4*(lane>>5). A: [m=lane&31][k=(lane>>5)*8+j];
//    B: [k=(lane>>5)*8+j][n=lane&31] (16x16-family pattern).
//  - Transposed convention (R7): GEMM1 S^T = K'xQ^T, softmax per-lane
//    (q=lane&31, 1 shfl_xor(32)); GEMM2 O^T = V'xP^T.
//  - K/V LDS transposed w/ XOR swizzle; P^T per-wave scratch PK=40 pad.
//  - XCD swizzle: 2 batches/XCD -> K/V working set ~4MB = per-XCD L2.

typedef __attribute__((ext_vector_type(8))) _Float16 f16x8;
typedef __attribute__((ext_vector_type(16))) float f32x16;

constexpr int Bz = 16;
constexpr int Nn = 2048;
constexpr int Dd = 128;
constexpr int BM = 128;  // q rows per block (4 consumer waves x 32)
constexpr int BN = 32;   // keys per iteration
constexpr int PK = 40;   // P^T row stride (ushorts), 32 + 8 pad

__device__ __forceinline__ int swz(int r) { return (r ^ (r >> 3)) & 7; }
__device__ __forceinline__ int sw4(int d) { return ((d >> 1) ^ (d >> 3)) & 3; }

__device__ __forceinline__ uint packh2(float a, float b) {
    union { _Float16 h[2]; uint u; } p;
    p.h[0] = (_Float16)a; p.h[1] = (_Float16)b;
    return p.u;
}

__global__ __launch_bounds__(512, 2)
void fattn_kernel(const float* __restrict__ qg,
                  const float* __restrict__ kg,
                  const float* __restrict__ vg,
                  float* __restrict__ og)
{
    __shared__ ushort lds_k[2][BN * Dd];   // [kk][d ^ (swz(kk)<<3)]  2 x 8 KB
    __shared__ ushort lds_v[2][Dd * BN];   // [d][kk ^ (sw4(d)<<3)]   2 x 8 KB
    __shared__ ushort lds_p[4][32 * PK];   // per-consumer-wave P^T [q][kk] 10 KB

    const int bid  = blockIdx.x;           // 256 blocks
    const int xcd  = bid & 7;
    const int idx  = bid >> 3;             // 0..31
    const int b    = xcd * 2 + (idx >> 4);
    const int q0   = (idx & 15) * BM;
    const int tid  = threadIdx.x;
    const int wv   = tid >> 6;             // 0..7
    const int lane = tid & 63;
    const int h    = lane >> 5;            // half-wave (k-slice)
    const int l31  = lane & 31;
    const bool producer = (wv >= 4);

    // ================= producer state =================
    const int ptid = (wv - 4) * 64 + lane;     // 0..255 (producers only)
    const int kgrp = ptid & 3;     // K: n-group (8 n's)
    const int krow = ptid >> 2;    // K: d-pair 0..63
    const int vgrp = ptid & 15;    // V: d-group (8 d's)
    const int vrow = ptid >> 4;    // V: kk-pair 0..15
    const float* kbase = kg + (size_t)b * Dd * Nn;
    const float* vbase = vg + (size_t)b * Nn * Dd;
    float4 kr[4], vr[4];

    auto issue_loads = [&](int n0) {
        const int d0 = krow * 2;
        const float* s0 = kbase + (size_t)d0 * Nn + n0 + kgrp * 8;
        kr[0] = ((const float4*)s0)[0];
        kr[1] = ((const float4*)s0)[1];
        kr[2] = ((const float4*)(s0 + Nn))[0];
        kr[3] = ((const float4*)(s0 + Nn))[1];
        const int kk0 = vrow * 2;
        const float* t0 = vbase + (size_t)(n0 + kk0) * Dd + vgrp * 8;
        vr[0] = ((const float4*)t0)[0];
        vr[1] = ((const float4*)t0)[1];
        vr[2] = ((const float4*)(t0 + Dd))[0];
        vr[3] = ((const float4*)(t0 + Dd))[1];
    };
    auto write_lds = [&](int buf) {
        uint* kw = (uint*)lds_k[buf];
        const float* av = (const float*)&kr[0];   // K row d0
        const float* bv = (const float*)&kr[2];   // K row d0+1
        #pragma unroll
        for (int j = 0; j < 8; ++j) {
            const int n = kgrp * 8 + j;
            kw[n * (Dd / 2) + (krow ^ (swz(n) << 2))] = packh2(av[j], bv[j]);
        }
        uint* vw = (uint*)lds_v[buf];
        const float* cv = (const float*)&vr[0];   // V row kk0
        const float* dv = (const float*)&vr[2];   // V row kk0+1
        #pragma unroll
        for (int j = 0; j < 8; ++j) {
            const int dd = vgrp * 8 + j;
            vw[dd * (BN / 2) + (vrow ^ (sw4(dd) << 2))] = packh2(cv[j], dv[j]);
        }
    };

    // ================= consumer state =================
    // Q^T as B-operand: lane holds Q[q = q0+wv*32+l31][d = c*16 + h*8 + j]
    f16x8 qf[8];
    if (!producer) {
        const float* qp = qg + (size_t)(b * Nn + q0 + wv * 32 + l31) * Dd + h * 8;
        #pragma unroll
        for (int c = 0; c < 8; ++c) {
            float4 x0 = *(const float4*)(qp + c * 16);
            float4 x1 = *(const float4*)(qp + c * 16 + 4);
            const float xv[8] = {x0.x, x0.y, x0.z, x0.w, x1.x, x1.y, x1.z, x1.w};
            union { f16x8 v; _Float16 e[8]; } u;
            #pragma unroll
            for (int j = 0; j < 8; ++j) u.e[j] = (_Float16)xv[j];
            qf[c] = u.v;
        }
    }
    f32x16 accO[4];   // O^T[dout = dt*32 + C-row][q = l31]
    #pragma unroll
    for (int dt = 0; dt < 4; ++dt)
        #pragma unroll
        for (int r = 0; r < 16; ++r) accO[dt][r] = 0.f;
    float m_i = -1e30f, l_i = 0.f;   // per-lane (q = l31; halves merged via shfl)

    // ================= pipeline =================
    if (producer) {
        issue_loads(0);
        write_lds(0);
    }
    __syncthreads();

    constexpr int ITERS = Nn / BN;   // 64
    for (int it = 0; it < ITERS; ++it) {
        const int cur = it & 1;
        if (producer) {
            if (it + 1 < ITERS) {
                issue_loads((it + 1) * BN);
                write_lds(cur ^ 1);
            }
        } else {
            const ushort* kb = lds_k[cur];
            const ushort* vb = lds_v[cur];

            // ---- S^T[kk=32][q=32] = K' x Q^T, K-dim 128 in 8 chunks ----
            f32x16 accS;
            #pragma unroll
            for (int r = 0; r < 16; ++r) accS[r] = 0.f;
            {
                const int kkrow = l31;
                const int sw = swz(kkrow) << 3;
                #pragma unroll
                for (int c = 0; c < 8; ++c) {
                    f16x8 kf = *(const f16x8*)&kb[kkrow * Dd + ((c * 16 + h * 8) ^ sw)];
                    accS = __builtin_amdgcn_mfma_f32_32x32x16_f16(kf, qf[c], accS, 0, 0, 0);
                }
            }

            // ---- online softmax, per-lane row (q = l31) ----
            float mx = accS[0];
            #pragma unroll
            for (int r = 1; r < 16; ++r) mx = fmaxf(mx, accS[r]);
            mx = fmaxf(mx, __shfl_xor(mx, 32, 64));
            const float mn = fmaxf(m_i, mx);
            const float alpha = __expf(m_i - mn);
            m_i = mn;
            float local = 0.f;
            #pragma unroll
            for (int r = 0; r < 16; ++r) {
                const float p = __expf(accS[r] - mn);
                accS[r] = p;
                local += p;
            }
            l_i = l_i * alpha + local;
            #pragma unroll
            for (int dt = 0; dt < 4; ++dt)
                #pragma unroll
                for (int r = 0; r < 16; ++r) accO[dt][r] *= alpha;

            // ---- P^T -> LDS [q][kk] (wave-private); C rows = 8g+4h+(0..3) ----
            ushort* pl = lds_p[wv];
            #pragma unroll
            for (int g = 0; g < 4; ++g) {
                uint2 w;
                w.x = packh2(accS[4 * g + 0], accS[4 * g + 1]);
                w.y = packh2(accS[4 * g + 2], accS[4 * g + 3]);
                *(uint2*)(pl + l31 * PK + 8 * g + 4 * h) = w;   // ds_write_b64
            }
            // B-frags: chunk c' of 16 kk: [q][16c' + 8h .. +8]
            f16x8 pf0 = *(const f16x8*)&pl[l31 * PK + 8 * h];
            f16x8 pf1 = *(const f16x8*)&pl[l31 * PK + 16 + 8 * h];

            // ---- O^T += V' x P^T : 4 dout tiles x 2 kk-chunks ----
            #pragma unroll
            for (int dt = 0; dt < 4; ++dt) {
                const int drow = dt * 32 + l31;
                const int sv = sw4(drow) << 3;
                f16x8 vf0 = *(const f16x8*)&vb[drow * BN + ((8 * h) ^ sv)];
                f16x8 vf1 = *(const f16x8*)&vb[drow * BN + ((16 + 8 * h) ^ sv)];
                accO[dt] = __builtin_amdgcn_mfma_f32_32x32x16_f16(vf0, pf0, accO[dt], 0, 0, 0);
                accO[dt] = __builtin_amdgcn_mfma_f32_32x32x16_f16(vf1, pf1, accO[dt], 0, 0, 0);
            }
        }
        __syncthreads();
    }

    // ================= epilogue (consumers) =================
    if (!producer) {
        float l = l_i + __shfl_xor(l_i, 32, 64);
        const float inv = 1.f / l;
        float* ob = og + (size_t)(b * Nn + q0 + wv * 32 + l31) * Dd;
        #pragma unroll
        for (int dt = 0; dt < 4; ++dt) {
            #pragma unroll
            for (int g = 0; g < 4; ++g) {
                float4 val;
                val.x = accO[dt][4 * g + 0] * inv;
                val.y = accO[dt][4 * g + 1] * inv;
                val.z = accO[dt][4 * g + 2] * inv;
                val.w = accO[dt][4 * g + 3] * inv;
                *(float4*)(ob + dt * 32 + 8 * g + 4 * h) = val;
            }
        }
    }
}

extern "C" void kernel_launch(void* const* d_in, const int* in_sizes, int n_in,
                              void* d_out, int out_size, void* d_ws, size_t ws_size,
                              hipStream_t stream) {
    const float* q = (const float*)d_in[0];
    const float* k = (const float*)d_in[1];
    const float* v = (const float*)d_in[2];
    float* o = (float*)d_out;
    (void)d_ws; (void)ws_size; (void)in_sizes; (void)n_in; (void)out_size;
    fattn_kernel<<<dim3(Bz * (Nn / BM)), dim3(512), 0, stream>>>(q, k, v, o);
}